// Round 7
// baseline (188.265 us; speedup 1.0000x reference)
//
#include <hip/hip_runtime.h>
#include <cstdint>
#include <cstddef>

typedef unsigned int u32;
typedef unsigned long long u64;

#define NTOT 122740      // total proposals (records) per batch
#define NPAIR 61370      // NTOT/2
#define KTOP 1024        // top-K kept per batch (deterministic bin-cutoff set)
#define WIN  256         // IoU-matrix window over the sorted list
#define NBIN 4096
#define SCORE_T 0.25f
#define TBITS 0x3E800000u       // bit pattern of 0.25f
#define HSPLIT_BITS 0x3EFFF000u // bits >= this  <=>  score_bin >= 2048
#define CSTRIDE 64              // counter padding (u32s); [0]=nH [1]=nL [8]=n_sorted
#define CAP_H 40960
#define CAP_L 20480

// concatenated float4 layout per batch (all level boundaries are f4-aligned):
//   L2: f4 [0,      138624)  p2, batch stride 138624 f4
//   L3: f4 [138624, 173280)  p3, stride 34656
//   L4: f4 [173280, 181944)  p4, stride 8664
//   L5: f4 [181944, 184110)  p5, stride 2166
#define F4TOT 184110
#define F4B3 138624
#define F4B4 173280
#define F4B5 181944

// ws layout (bytes):
//   counters: 32*64*4   = 8192      @ 0
//   sortedK:  32*1024*8 = 262144    @ 8192
//   candH:    32*CAP_H*8= 10485760  @ 270336
//   candL:    32*CAP_L*8= 5242880   @ 10756096   (end ~16.0 MB)
#define WS_SORTED 8192
#define WS_CANDH  270336
#define WS_CANDL  10756096

// ---------------------------------------------------------------- helpers
__device__ __forceinline__ float sigm(float x) { return 1.0f / (1.0f + expf(-x)); }

__device__ __forceinline__ int score_bin(u32 bits) {
  return min(4095, 1 + (int)((bits - TBITS) >> 12));
}

__device__ __forceinline__ u64 shfl_u64(u64 x, int src) {
  int lo = __shfl((int)(u32)x, src, 64);
  int hi = __shfl((int)(u32)(x >> 32), src, 64);
  return ((u64)(u32)hi << 32) | (u32)lo;
}

// scores for record pair P (records 2P, 2P+1) of batch b  (fallback path only)
__device__ __forceinline__ void score_pair(int P, int b,
    const float* __restrict__ p2, const float* __restrict__ p3,
    const float* __restrict__ p4, const float* __restrict__ p5,
    u32& b0, u32& b1, u32& gi0, u32& gi1)
{
  int t0 = 2 * P;
  const float* p; int l0, LN;
  if (t0 < 92416)       { p = p2; l0 = t0;          LN = 92416; }
  else if (t0 < 115520) { p = p3; l0 = t0 - 92416;  LN = 23104; }
  else if (t0 < 121296) { p = p4; l0 = t0 - 115520; LN = 5776;  }
  else                  { p = p5; l0 = t0 - 121296; LN = 1444;  }
  const float* q = p + ((size_t)b * LN + (size_t)l0) * 6;
  float4 v1 = *(const float4*)(q + 4);
  float4 v2 = *(const float4*)(q + 8);
  float s0 = sigm(v1.x) * sigm(v1.y);
  float s1 = sigm(v2.z) * sigm(v2.w);
  b0 = (s0 >= SCORE_T) ? __float_as_uint(s0) : 0u;
  b1 = (s1 >= SCORE_T) ? __float_as_uint(s1) : 0u;
  gi0 = (u32)t0; gi1 = (u32)(t0 + 1);
}

__device__ float4 decode_box_from_gidx(u32 gidx, int b,
    const float* __restrict__ p2, const float* __restrict__ p3,
    const float* __restrict__ p4, const float* __restrict__ p5)
{
  const float* p; int t, H, W; float stride;
  float aw0, ah0, aw1, ah1, aw2, ah2, aw3, ah3;
  if (gidx < 92416u) {
    p = p2 + (size_t)b * 92416 * 6; t = (int)gidx; H = 152; W = 152; stride = 4.0f;
    aw0=12.f; ah0=16.f; aw1=19.f; ah1=36.f; aw2=40.f; ah2=28.f; aw3=36.f; ah3=75.f;
  } else if (gidx < 115520u) {
    p = p3 + (size_t)b * 23104 * 6; t = (int)(gidx - 92416u); H = 76; W = 76; stride = 8.0f;
    aw0=36.f; ah0=75.f; aw1=76.f; ah1=55.f; aw2=72.f; ah2=146.f; aw3=142.f; ah3=110.f;
  } else if (gidx < 121296u) {
    p = p4 + (size_t)b * 5776 * 6; t = (int)(gidx - 115520u); H = 38; W = 38; stride = 16.0f;
    aw0=72.f; ah0=146.f; aw1=142.f; ah1=110.f; aw2=192.f; ah2=243.f; aw3=459.f; ah3=401.f;
  } else {
    p = p5 + (size_t)b * 1444 * 6; t = (int)(gidx - 121296u); H = 19; W = 19; stride = 32.0f;
    aw0=142.f; ah0=110.f; aw1=192.f; ah1=243.f; aw2=300.f; ah2=300.f; aw3=459.f; ah3=401.f;
  }
  int HW = H * W;
  int a = t / HW;
  int r = t - a * HW;
  int y = r / W;
  int x = r - y * W;
  const float* q = p + (size_t)t * 6;
  float2 t01 = *(const float2*)(q + 0);
  float2 t23 = *(const float2*)(q + 2);
  float cx = (sigm(t01.x) + (float)x) * stride;
  float cy = (sigm(t01.y) + (float)y) * stride;
  float aw = (a == 0) ? aw0 : (a == 1) ? aw1 : (a == 2) ? aw2 : aw3;
  float ah = (a == 0) ? ah0 : (a == 1) ? ah1 : (a == 2) ? ah2 : ah3;
  float bw = expf(t23.x) * aw;
  float bh = expf(t23.y) * ah;
  return make_float4(cx - 0.5f * bw, cy - 0.5f * bh, cx + 0.5f * bw, cy + 0.5f * bh);
}

__device__ __forceinline__ bool iou_gt(float4 A, float4 B) {
  float ltx = fmaxf(A.x, B.x), lty = fmaxf(A.y, B.y);
  float rbx = fminf(A.z, B.z), rby = fminf(A.w, B.w);
  float w = fmaxf(rbx - ltx, 0.0f), h = fmaxf(rby - lty, 0.0f);
  float inter = w * h;
  float a1 = fmaxf(A.z - A.x, 0.0f) * fmaxf(A.w - A.y, 0.0f);
  float a2 = fmaxf(B.z - B.x, 0.0f) * fmaxf(B.w - B.y, 0.0f);
  float iou = inter / (a1 + a2 - inter + 1e-9f);
  return iou > 0.5f;
}

// ---------------------------------------------------------------- A: decode (dense LDS-transpose)
// grid (240, 32), 256 thr. Block stages 768 CONSECUTIVE float4 (512 records)
// into LDS with fully coalesced wave loads, then reads conf/cls from LDS.
__global__ __launch_bounds__(256)
void decode_kernel(const float* __restrict__ p2, const float* __restrict__ p3,
                   const float* __restrict__ p4, const float* __restrict__ p5,
                   u32* __restrict__ counters,
                   uint2* __restrict__ candH, uint2* __restrict__ candL)
{
  __shared__ float4 sbuf4[768];           // 12 KB
  __shared__ uint2 stH[512];              // 4 KB
  __shared__ uint2 stL[512];              // 4 KB
  __shared__ u32 s_cH, s_cL, s_bH, s_bL;
  const int tid = threadIdx.x;
  const int b = blockIdx.y;
  if (tid == 0) { s_cH = 0u; s_cL = 0u; }

  const float4* q2 = (const float4*)p2;
  const float4* q3 = (const float4*)p3;
  const float4* q4 = (const float4*)p4;
  const float4* q5 = (const float4*)p5;

  const int f4base = blockIdx.x * 768;
  #pragma unroll
  for (int j = 0; j < 3; ++j) {
    int idx4 = f4base + j * 256 + tid;
    if (idx4 < F4TOT) {
      const float4* src;
      if (idx4 < F4B3)      src = q2 + (size_t)b * 138624 + idx4;
      else if (idx4 < F4B4) src = q3 + (size_t)b * 34656  + (idx4 - F4B3);
      else if (idx4 < F4B5) src = q4 + (size_t)b * 8664   + (idx4 - F4B4);
      else                  src = q5 + (size_t)b * 2166   + (idx4 - F4B5);
      sbuf4[j * 256 + tid] = *src;
    }
  }
  __syncthreads();

  const float* sbuf = (const float*)sbuf4;
  const int rbase = blockIdx.x * 512;
  #pragma unroll
  for (int k = 0; k < 2; ++k) {
    int lr = 2 * tid + k;                 // local record 0..511
    int rg = rbase + lr;                  // global concat record index
    if (rg < NTOT) {
      float2 cc = *(const float2*)&sbuf[lr * 6 + 4];   // conf, cls
      float s = sigm(cc.x) * sigm(cc.y);
      if (s >= SCORE_T) {
        u32 bits = __float_as_uint(s);
        bool H = (bits >= HSPLIT_BITS);
        u32 pos = atomicAdd(H ? &s_cH : &s_cL, 1u);
        if (pos < 512u) (H ? stH : stL)[pos] = make_uint2(bits, (u32)rg);
      }
    }
  }
  __syncthreads();
  if (tid == 0) {
    if (s_cH) s_bH = atomicAdd(&counters[(size_t)b * CSTRIDE],     s_cH);
    if (s_cL) s_bL = atomicAdd(&counters[(size_t)b * CSTRIDE + 1], s_cL);
  }
  __syncthreads();
  uint2* gH = candH + (size_t)b * CAP_H;
  uint2* gL = candL + (size_t)b * CAP_L;
  const u32 mH = min(s_cH, 512u), mL = min(s_cL, 512u);
  for (u32 i = tid; i < mH; i += 256) { u32 d = s_bH + i; if (d < (u32)CAP_H) gH[d] = stH[i]; }
  for (u32 i = tid; i < mL; i += 256) { u32 d = s_bL + i; if (d < (u32)CAP_L) gL[d] = stL[i]; }
}

// ---------------------------------------------------------------- S: hist + scan + scatter + rank-sort
// One block per batch. Writes exactly-sorted keys (desc) to sortedK and n to counters[8].
__global__ __launch_bounds__(1024, 1)
void sort_kernel(const u32* __restrict__ counters_in, u32* __restrict__ counters,
                 const uint2* __restrict__ candH, const uint2* __restrict__ candL,
                 const float* __restrict__ p2, const float* __restrict__ p3,
                 const float* __restrict__ p4, const float* __restrict__ p5,
                 u64* __restrict__ sortedK)
{
  const int b = blockIdx.x;
  const int tid = threadIdx.x;

  __shared__ u32 sstart[NBIN];      // 16 KB  cnt_ge(bin+1)
  __shared__ u32 scur[NBIN];        // 16 KB  hist, then cursors
  __shared__ u64 skey[KTOP];        // 8 KB   bin-grouped keys
  __shared__ int s_B, s_n;

  const u32 nHc = counters_in[(size_t)b * CSTRIDE];
  const u32 nLc = counters_in[(size_t)b * CSTRIDE + 1];
  const bool readL = (nHc < (u32)KTOP);
  const bool fb = (nHc > (u32)CAP_H) || (readL && nLc > (u32)CAP_L);

  for (int i = tid; i < NBIN; i += 1024) scur[i] = 0u;
  __syncthreads();

  // ---- phase A: histogram
  if (!fb) {
    const uint2* gH = candH + (size_t)b * CAP_H;
    for (u32 i = tid; i < nHc; i += 1024) atomicAdd(&scur[score_bin(gH[i].x)], 1u);
    if (readL) {
      const uint2* gL = candL + (size_t)b * CAP_L;
      for (u32 i = tid; i < nLc; i += 1024) atomicAdd(&scur[score_bin(gL[i].x)], 1u);
    }
  } else {
    for (int P = tid; P < NPAIR; P += 1024) {
      u32 b0, b1, gi0, gi1;
      score_pair(P, b, p2, p3, p4, p5, b0, b1, gi0, gi1);
      if (b0) atomicAdd(&scur[score_bin(b0)], 1u);
      if (b1) atomicAdd(&scur[score_bin(b1)], 1u);
    }
  }
  __syncthreads();

  // ---- phase B: wave-0 shfl suffix scan + in-wave min-reduce for cutoff
  if (tid < 64) {
    u32 h[64];
    #pragma unroll
    for (int k = 0; k < 64; ++k) h[k] = scur[tid * 64 + k];
    u32 lsum = 0;
    #pragma unroll
    for (int k = 0; k < 64; ++k) lsum += h[k];
    u32 S = lsum;
    #pragma unroll
    for (int off = 1; off < 64; off <<= 1) {
      u32 v = (u32)__shfl_down((int)S, off, 64);
      if (tid + off < 64) S += v;
    }
    u32 c = S - lsum;                           // cnt_ge(64*tid + 64)
    int Bv = -1; u32 nv = 0;
    for (int k = 63; k >= 0; --k) {
      sstart[tid * 64 + k] = c;                 // cnt_ge(bin+1)
      c += h[k];                                // cnt_ge(bin)
      if (c <= (u32)KTOP) { Bv = tid * 64 + k; nv = c; }
    }
    u32 pk = (Bv < 0) ? 0xFFFFFFFFu : (((u32)Bv << 12) | nv);   // nv <= 1024 fits 12b
    #pragma unroll
    for (int off = 32; off >= 1; off >>= 1) {
      u32 o = (u32)__shfl_down((int)pk, off, 64);
      if (tid + off < 64) pk = min(pk, o);
    }
    if (tid == 0) {
      if (pk == 0xFFFFFFFFu) { s_B = 4095; s_n = KTOP; }   // unreachable
      else { s_B = max((int)(pk >> 12), 1); s_n = (int)(pk & 0xFFFu); }
    }
  }
  __syncthreads();
  const int B = s_B;
  const int n = min(s_n, KTOP);

  for (int i = tid; i < NBIN; i += 1024) scur[i] = sstart[i];
  __syncthreads();

  // ---- phase C: scatter survivors (bin >= B) into counting slots
  if (!fb) {
    const uint2* gH = candH + (size_t)b * CAP_H;
    for (u32 i = tid; i < nHc; i += 1024) {
      uint2 e = gH[i];
      int bin = score_bin(e.x);
      if (bin >= B) {
        u32 slot = atomicAdd(&scur[bin], 1u);
        if (slot < (u32)KTOP) skey[slot] = ((u64)e.x << 32) | (u32)(~e.y);
      }
    }
    if (readL) {
      const uint2* gL = candL + (size_t)b * CAP_L;
      for (u32 i = tid; i < nLc; i += 1024) {
        uint2 e = gL[i];
        int bin = score_bin(e.x);
        if (bin >= B) {
          u32 slot = atomicAdd(&scur[bin], 1u);
          if (slot < (u32)KTOP) skey[slot] = ((u64)e.x << 32) | (u32)(~e.y);
        }
      }
    }
  } else {
    for (int P = tid; P < NPAIR; P += 1024) {
      u32 b0, b1, gi0, gi1;
      score_pair(P, b, p2, p3, p4, p5, b0, b1, gi0, gi1);
      if (b0) { int bin = score_bin(b0);
        if (bin >= B) { u32 slot = atomicAdd(&scur[bin], 1u);
          if (slot < (u32)KTOP) skey[slot] = ((u64)b0 << 32) | (u32)(~gi0); } }
      if (b1) { int bin = score_bin(b1);
        if (bin >= B) { u32 slot = atomicAdd(&scur[bin], 1u);
          if (slot < (u32)KTOP) skey[slot] = ((u64)b1 << 32) | (u32)(~gi1); } }
    }
  }
  __syncthreads();

  // ---- phase D: exact rank sort within bins -> global sortedK (desc)
  u64* dst = sortedK + (size_t)b * KTOP;
  for (int s = tid; s < n; s += 1024) {
    u64 k = skey[s];
    int bin = score_bin((u32)(k >> 32));
    int st = (int)sstart[bin];
    int en = (int)scur[bin];
    u32 r = 0;
    for (int j = st; j < en; ++j) r += (skey[j] > k) ? 1u : 0u;
    dst[st + r] = k;
  }
  if (tid == 0) counters[(size_t)b * CSTRIDE + 8] = (u32)n;
}

// ---------------------------------------------------------------- N: window decode + IoU + greedy NMS
__global__ __launch_bounds__(1024, 1)
void nms_kernel(const u32* __restrict__ counters, const u64* __restrict__ sortedK,
                const float* __restrict__ p2, const float* __restrict__ p3,
                const float* __restrict__ p4, const float* __restrict__ p5,
                float* __restrict__ out)
{
  const int b = blockIdx.x;
  const int tid = threadIdx.x;

  __shared__ u64 skeyw[WIN];        // 2 KB   window keys
  __shared__ float4 sbox[WIN];      // 4 KB
  __shared__ u64 smat[WIN * 4];     // 8 KB   [word][row]
  __shared__ float4 selbox[100];    // 1.6 KB
  __shared__ int s_misc[4];         // [2]=n_sel, [3]=need slow

  const int n = min((int)counters[(size_t)b * CSTRIDE + 8], KTOP);
  const u64* src = sortedK + (size_t)b * KTOP;
  const int Wn = min(n, WIN);

  // ---- window keys + boxes
  if (tid < WIN) {
    u64 k = (tid < Wn) ? src[tid] : 0ull;
    skeyw[tid] = k;
    sbox[tid] = (tid < Wn) ? decode_box_from_gidx(~(u32)k, b, p2, p3, p4, p5)
                           : make_float4(0.f, 0.f, 0.f, 0.f);
  }
  __syncthreads();

  // ---- IoU bitmask matrix; row = tid&255, word = tid>>8 (broadcast reads)
  {
    int row = tid & 255, word = tid >> 8;
    u64 bits = 0;
    if (row < Wn) {
      float4 A = sbox[row];
      int j0 = word * 64;
      int je = min(64, Wn - j0);
      for (int j = 0; j < je; ++j)
        if (iou_gt(A, sbox[j0 + j])) bits |= (1ull << j);
    }
    smat[word * 256 + row] = bits;
  }
  __syncthreads();

  // ---- greedy selection on wave 0, matrix rows in registers
  if (tid < 64) {
    const int lane = tid;
    u64 m0[4], m1[4], m2[4], m3[4];
    #pragma unroll
    for (int w = 0; w < 4; ++w) {
      m0[w] = smat[w * 256 +   0 + lane];
      m1[w] = smat[w * 256 +  64 + lane];
      m2[w] = smat[w * 256 + 128 + lane];
      m3[w] = smat[w * 256 + 192 + lane];
    }
    u64 live[4];
    #pragma unroll
    for (int g2 = 0; g2 < 4; ++g2) {
      int lo = g2 * 64;
      live[g2] = (Wn >= lo + 64) ? ~0ull : (Wn > lo ? ((1ull << (Wn - lo)) - 1ull) : 0ull);
    }
    int sel = 0;
    #pragma unroll 1
    for (int w2 = 0; w2 < 4; ++w2) {
      while (live[w2] && sel < 100) {
        int j = (int)__ffsll(live[w2]) - 1;
        int p = (w2 << 6) + j;
        u64 r0, r1, r2, r3;
        if (w2 == 0)      { r0 = shfl_u64(m0[0], j); r1 = shfl_u64(m0[1], j); r2 = shfl_u64(m0[2], j); r3 = shfl_u64(m0[3], j); }
        else if (w2 == 1) { r0 = shfl_u64(m1[0], j); r1 = shfl_u64(m1[1], j); r2 = shfl_u64(m1[2], j); r3 = shfl_u64(m1[3], j); }
        else if (w2 == 2) { r0 = shfl_u64(m2[0], j); r1 = shfl_u64(m2[1], j); r2 = shfl_u64(m2[2], j); r3 = shfl_u64(m2[3], j); }
        else              { r0 = shfl_u64(m3[0], j); r1 = shfl_u64(m3[1], j); r2 = shfl_u64(m3[2], j); r3 = shfl_u64(m3[3], j); }
        live[0] &= ~r0; live[1] &= ~r1; live[2] &= ~r2; live[3] &= ~r3;
        live[w2] &= ~(1ull << j);
        if (lane == 0) {
          float4 box = sbox[p];
          u64 k = skeyw[p];
          float sc = __uint_as_float((u32)(k >> 32));
          selbox[sel] = box;
          float* orow = out + (size_t)b * 500 + (size_t)sel * 5;
          orow[0] = box.x; orow[1] = box.y; orow[2] = box.z; orow[3] = box.w; orow[4] = sc;
        }
        sel++;
      }
    }
    if (lane == 0) {
      s_misc[2] = sel;
      s_misc[3] = (sel < 100 && n > WIN) ? 1 : 0;
    }
  }
  __syncthreads();

  // ---- exact slow path beyond the window (statistically never taken)
  if (s_misc[3]) {
    if (tid < 64) {
      const int lane = tid;
      int sel = s_misc[2];
      for (int p = WIN; p < n && sel < 100; ++p) {
        u64 k = src[p];
        float4 box = decode_box_from_gidx(~(u32)k, b, p2, p3, p4, p5);
        bool hit = false;
        if (lane < sel) hit = iou_gt(selbox[lane], box);
        if (lane + 64 < sel) hit = hit || iou_gt(selbox[lane + 64], box);
        u64 anyhit = __ballot(hit);
        if (anyhit == 0ull) {
          if (lane == 0) {
            selbox[sel] = box;
            float sc = __uint_as_float((u32)(k >> 32));
            float* orow = out + (size_t)b * 500 + (size_t)sel * 5;
            orow[0] = box.x; orow[1] = box.y; orow[2] = box.z; orow[3] = box.w; orow[4] = sc;
          }
          sel++;
        }
      }
      if (lane == 0) s_misc[2] = sel;
    }
  }
  __syncthreads();

  // ---- zero-fill remaining rows
  const int nsel = s_misc[2];
  for (int i = tid; i < (100 - nsel) * 5; i += 1024)
    out[(size_t)b * 500 + (size_t)nsel * 5 + i] = 0.0f;
}

// ---------------------------------------------------------------- launch
extern "C" void kernel_launch(void* const* d_in, const int* in_sizes, int n_in,
                              void* d_out, int out_size, void* d_ws, size_t ws_size,
                              hipStream_t stream) {
  const float* p2 = (const float*)d_in[0];
  const float* p3 = (const float*)d_in[1];
  const float* p4 = (const float*)d_in[2];
  const float* p5 = (const float*)d_in[3];
  float* out = (float*)d_out;

  unsigned char* w = (unsigned char*)d_ws;
  u32*   counters = (u32*)w;
  u64*   sortedK  = (u64*)(w + WS_SORTED);
  uint2* candH    = (uint2*)(w + WS_CANDH);
  uint2* candL    = (uint2*)(w + WS_CANDL);

  hipMemsetAsync(counters, 0, 32 * CSTRIDE * sizeof(u32), stream);
  decode_kernel<<<dim3(240, 32), 256, 0, stream>>>(p2, p3, p4, p5,
                                                   counters, candH, candL);
  sort_kernel<<<32, 1024, 0, stream>>>(counters, counters, candH, candL,
                                       p2, p3, p4, p5, sortedK);
  nms_kernel<<<32, 1024, 0, stream>>>(counters, sortedK, p2, p3, p4, p5, out);
}